// Round 3
// baseline (1404.087 us; speedup 1.0000x reference)
//
#include <hip/hip_runtime.h>
#include <cstdint>
#include <cstddef>

// out[m,n] = scale[m]*wscale[n]*(sum_k q[m,k]*w8[n,k] - azp[m]*azp_adj[n]) + bias[n]
// M=8192, K=4096, N=4096. Exact int8 path.

#define M_DIM 8192
#define K_DIM 4096
#define N_DIM 4096
#define NT (K_DIM / 64)   // 64 K-tiles of BK=64

typedef int v4i __attribute__((ext_vector_type(4)));

// ---------------------------------------------------------------------------
// Kernel 1 (fused): blocks [0, M) do per-token quant; blocks [M, M+N) do
// weight prep. Bit-identical math to the verified standalone kernels.
// ---------------------------------------------------------------------------
__global__ __launch_bounds__(256) void prep_kernel(
    const float* __restrict__ x, signed char* __restrict__ q,
    float* __restrict__ scale_out, int* __restrict__ azp_out,
    const int* __restrict__ w, signed char* __restrict__ w8,
    int* __restrict__ azp_adj)
{
    const int t = threadIdx.x;
    if (blockIdx.x < M_DIM) {
        // ---- per-token asymmetric quantization, one block per row ----
        const int m = blockIdx.x;
        const float4* row4 = (const float4*)(x + (size_t)m * K_DIM);

        float4 v[4];
        float mx = -3.4e38f, mn = 3.4e38f;
#pragma unroll
        for (int i = 0; i < 4; ++i) {
            v[i] = row4[i * 256 + t];                  // coalesced
            mx = fmaxf(mx, fmaxf(fmaxf(v[i].x, v[i].y), fmaxf(v[i].z, v[i].w)));
            mn = fminf(mn, fminf(fminf(v[i].x, v[i].y), fminf(v[i].z, v[i].w)));
        }
#pragma unroll
        for (int off = 32; off; off >>= 1) {
            mx = fmaxf(mx, __shfl_down(mx, off));
            mn = fminf(mn, __shfl_down(mn, off));
        }
        __shared__ float smx[4], smn[4];
        if ((t & 63) == 0) { smx[t >> 6] = mx; smn[t >> 6] = mn; }
        __syncthreads();
        mx = fmaxf(fmaxf(smx[0], smx[1]), fmaxf(smx[2], smx[3]));
        mn = fminf(fminf(smn[0], smn[1]), fminf(smn[2], smn[3]));

        const float scale = (mx - mn) / 255.0f;
        const int azp = (int)rintf(-128.0f - mn / scale);
        if (t == 0) { scale_out[m] = scale; azp_out[m] = azp; }

        int* qrow = (int*)(q + (size_t)m * K_DIM);
        const float* vf = (const float*)v;
#pragma unroll
        for (int i = 0; i < 4; ++i) {
            int b[4];
#pragma unroll
            for (int j = 0; j < 4; ++j) {
                int qv = (int)rintf(vf[4 * i + j] / scale) + azp;
                qv = qv < -128 ? -128 : (qv > 127 ? 127 : qv);
                b[j] = qv;
            }
            qrow[i * 256 + t] =
                (b[0] & 255) | ((b[1] & 255) << 8) | ((b[2] & 255) << 16) | ((b[3] & 255) << 24);
        }
    } else {
        // ---- weight prep: int32 [N,K] -> int8 [N,K] + column sums ----
        const int n = blockIdx.x - M_DIM;
        const int4* row = (const int4*)(w + (size_t)n * K_DIM);
        int* w8row = (int*)(w8 + (size_t)n * K_DIM);
        int sum = 0;
#pragma unroll
        for (int i = 0; i < 4; ++i) {
            int4 a = row[i * 256 + t];                 // coalesced
            sum += a.x + a.y + a.z + a.w;
            w8row[i * 256 + t] =
                (a.x & 255) | ((a.y & 255) << 8) | ((a.z & 255) << 16) | ((a.w & 255) << 24);
        }
#pragma unroll
        for (int off = 32; off; off >>= 1) sum += __shfl_down(sum, off);
        __shared__ int ssum[4];
        if ((t & 63) == 0) ssum[t >> 6] = sum;
        __syncthreads();
        if (t == 0) azp_adj[n] = ssum[0] + ssum[1] + ssum[2] + ssum[3];
    }
}

// ---------------------------------------------------------------------------
// Kernel 2: int8 GEMM, 256x256 tile, BK=64, 8 waves (2M x 4N), per-wave
// 128x64 via mfma_i32_16x16x64_i8.
//
// Round-3 change: 2-deep LDS double buffer (64 KiB total) -> 2 resident
// blocks/CU (was 128 KiB ring -> 1 block/CU). Two independent barrier
// domains per CU: while block X is in a barrier-lockstep read region, block
// Y feeds the matrix pipe (m114 cross-wave MFMA||LDS co-scheduling). Phase
// structure is round-1's proven template shape (the round-2 coarse split
// regressed, per m196):
//   ph1: 8 ds_read_b128 (af,bf); 4 global_load_lds (ALL of tile kt+1);
//        barrier; lgkmcnt(0); setprio(1); 16 MFMA; setprio(0); barrier
//   ph2: 4 ds_read_b128 (ah); barrier; lgkmcnt(0); setprio(1); 16 MFMA;
//        setprio(0); vmcnt(0); barrier
// Stage loads get a full tile (~1500 cy) in flight before the vmcnt(0), so
// the wait is the fixed ~330 cy drain, hidden by the sibling block.
//
// Ring-race safety (dbuf-2, distance 1):
//   - stage(kt+1) writes buf cur^1, last READ during tile kt-1; those reads
//     drained by tile kt-1's per-phase lgkmcnt(0) before its end barrier,
//     and the stage is issued only after this wave passed that barrier.
//   - reads of buf cur (tile kt) staged during tile kt-1, sealed by the
//     end-of-tile vmcnt(0) (per-wave own-load drain) + barrier.
//   - XOR swizzle byte-identical to the proven kernel (0 conflicts measured):
//     LDS granule (row,c) holds global (row, c ^ ((row>>1)&3)); staging
//     pre-swizzles the GLOBAL address (LDS dst linear, mandatory for
//     global_load_lds); read swizzle collapses to quad ^ ((r16>>1)&3).
//   - XCD-aware bijective block swizzle (512 blocks, 512 % 8 == 0).
// ---------------------------------------------------------------------------
__device__ __forceinline__ void async_copy16(const signed char* g, signed char* l) {
    __builtin_amdgcn_global_load_lds(
        (const __attribute__((address_space(1))) void*)g,
        (__attribute__((address_space(3))) void*)l, 16, 0, 0);
}

__device__ __forceinline__ void tile_step(
    int kt, const v4i* a4, const v4i* b4,          // current buffers
    signed char* sAd, signed char* sBd,            // destination buffers
    const signed char* ag0, const signed char* ag1,
    const signed char* bg0, const signed char* bg1,
    int t, int aIdx, int bIdx, v4i (&acc)[8][4])
{
    // ---- phase 1: reads first, then all 4 stage loads for tile kt+1 ----
    v4i af[4], bf[4];
#pragma unroll
    for (int i = 0; i < 4; ++i) {
        af[i] = a4[aIdx + i * 64];           // rows wm   + i*16 + r16
        bf[i] = b4[bIdx + i * 64];           // rows wn   + i*16 + r16
    }
    if (kt < NT - 1) {
        const int ko = (kt + 1) << 6;
        async_copy16(ag0 + ko, sAd + t * 16);
        async_copy16(ag1 + ko, sAd + 8192 + t * 16);
        async_copy16(bg0 + ko, sBd + t * 16);
        async_copy16(bg1 + ko, sBd + 8192 + t * 16);
    }
    __builtin_amdgcn_s_barrier();
    asm volatile("s_waitcnt lgkmcnt(0)" ::: "memory");
    __builtin_amdgcn_s_setprio(1);
#pragma unroll
    for (int i = 0; i < 4; ++i)
#pragma unroll
        for (int j = 0; j < 4; ++j)
            acc[i][j] = __builtin_amdgcn_mfma_i32_16x16x64_i8(af[i], bf[j], acc[i][j], 0, 0, 0);
    __builtin_amdgcn_s_setprio(0);
    __builtin_amdgcn_s_barrier();

    // ---- phase 2: m-half 1 (B frags reused from registers) ----
    v4i ah[4];
#pragma unroll
    for (int i = 0; i < 4; ++i)
        ah[i] = a4[aIdx + 256 + i * 64];     // rows wm+64+i*16+r16
    __builtin_amdgcn_s_barrier();
    asm volatile("s_waitcnt lgkmcnt(0)" ::: "memory");
    __builtin_amdgcn_s_setprio(1);
#pragma unroll
    for (int i = 0; i < 4; ++i)
#pragma unroll
        for (int j = 0; j < 4; ++j)
            acc[4 + i][j] = __builtin_amdgcn_mfma_i32_16x16x64_i8(ah[i], bf[j], acc[4 + i][j], 0, 0, 0);
    __builtin_amdgcn_s_setprio(0);

    // ---- end of tile: seal next tile's stages (own-load drain + barrier) ----
    if (kt < NT - 1) {
        asm volatile("s_waitcnt vmcnt(0)" ::: "memory");
        __builtin_amdgcn_s_barrier();
    }
}

__global__ __launch_bounds__(512, 4) void gemm_kernel(
    const signed char* __restrict__ A,   // [M,K] quantized activations
    const signed char* __restrict__ B,   // [N,K] int8 weights
    const float* __restrict__ scale, const int* __restrict__ azp,
    const int* __restrict__ azp_adj, const float* __restrict__ wscale,
    const float* __restrict__ bias, float* __restrict__ out)
{
    __shared__ signed char sA[2][16384];   // 2-deep dbuf x 256 rows x 64B
    __shared__ signed char sB[2][16384];   // total 64 KiB -> 2 blocks/CU

    const int t = threadIdx.x;
    const int lane = t & 63;
    const int wave = t >> 6;
    const int quad = lane >> 4;
    const int r16 = lane & 15;

    // XCD-aware swizzle over the 512 blocks (bijective since 512 % 8 == 0)
    int bid = blockIdx.y * gridDim.x + blockIdx.x;
    bid = (bid & 7) * 64 + (bid >> 3);
    const int bn = (bid & 15) << 8;        // 16 n-blocks
    const int bm = (bid >> 4) << 8;        // 32 m-blocks

    const int wm = (wave >> 2) << 7;       // 0 or 128
    const int wn = (wave & 3) << 6;        // 0,64,128,192

    v4i acc[8][4];
#pragma unroll
    for (int i = 0; i < 8; ++i)
#pragma unroll
        for (int j = 0; j < 4; ++j) acc[i][j] = (v4i){0, 0, 0, 0};

    // staging: thread t fills LDS granule t of a 128-row chunk (row = t>>2,
    // colL = t&3); global col = colL ^ ((row>>1)&3) = (t&3) ^ ((t>>3)&3).
    const int srow = t >> 2;                               // 0..127
    const int scol = ((t & 3) ^ ((t >> 3) & 3)) << 4;      // pre-swizzled global col
    const signed char* ag0 = A + (size_t)(bm + srow) * K_DIM + scol;
    const signed char* ag1 = A + (size_t)(bm + 128 + srow) * K_DIM + scol;
    const signed char* bg0 = B + (size_t)(bn + srow) * K_DIM + scol;
    const signed char* bg1 = B + (size_t)(bn + 128 + srow) * K_DIM + scol;

    // per-lane LDS read indices (v4i granule units); swizzle collapses to a
    // per-lane constant since wm/wn/i*16 are 0 mod 8.
    const int swz = quad ^ ((r16 >> 1) & 3);
    const int aIdx = (wm + r16) * 4 + swz;   // granule index within one buffer
    const int bIdx = (wn + r16) * 4 + swz;

    // prologue: stage tile 0 into buf 0, seal it
    async_copy16(ag0, &sA[0][t * 16]);
    async_copy16(ag1, &sA[0][8192 + t * 16]);
    async_copy16(bg0, &sB[0][t * 16]);
    async_copy16(bg1, &sB[0][8192 + t * 16]);
    asm volatile("s_waitcnt vmcnt(0)" ::: "memory");
    __builtin_amdgcn_s_barrier();

    // main loop, 2x unrolled so buffer indices are compile-time (rule 20)
    for (int kt = 0; kt < NT; kt += 2) {
        tile_step(kt,     (const v4i*)&sA[0][0], (const v4i*)&sB[0][0],
                  &sA[1][0], &sB[1][0], ag0, ag1, bg0, bg1, t, aIdx, bIdx, acc);
        tile_step(kt + 1, (const v4i*)&sA[1][0], (const v4i*)&sB[1][0],
                  &sA[0][0], &sB[0][0], ag0, ag1, bg0, bg1, t, aIdx, bIdx, acc);
    }

    // epilogue: out = scale[m]*wscale[n]*(acc - azp[m]*adj[n]) + bias[n]
#pragma unroll
    for (int i = 0; i < 8; ++i) {
        const int mbase = bm + wm + i * 16 + quad * 4;
        float sm[4]; int am[4];
#pragma unroll
        for (int r = 0; r < 4; ++r) { sm[r] = scale[mbase + r]; am[r] = azp[mbase + r]; }
#pragma unroll
        for (int j = 0; j < 4; ++j) {
            const int n = bn + wn + j * 16 + r16;
            const float wsn = wscale[n];
            const int adjn = azp_adj[n];
            const float bn_ = bias[n];
#pragma unroll
            for (int r = 0; r < 4; ++r) {
                const int c = acc[i][j][r] - am[r] * adjn;
                out[(size_t)(mbase + r) * N_DIM + n] = sm[r] * wsn * (float)c + bn_;
            }
        }
    }
}

// ---------------------------------------------------------------------------
extern "C" void kernel_launch(void* const* d_in, const int* in_sizes, int n_in,
                              void* d_out, int out_size, void* d_ws, size_t ws_size,
                              hipStream_t stream) {
    const float* x      = (const float*)d_in[0];
    const int*   w      = (const int*)d_in[1];
    const float* wscale = (const float*)d_in[2];
    const float* bias   = (const float*)d_in[3];
    float* out = (float*)d_out;

    char* ws = (char*)d_ws;
    signed char* q8  = (signed char*)ws;                         // 32 MiB
    signed char* w8  = (signed char*)(ws + 33554432);            // 16 MiB
    float* scl       = (float*)(ws + 50331648);                  // 32 KiB
    int*   azp       = (int*)(ws + 50331648 + 32768);            // 32 KiB
    int*   adj       = (int*)(ws + 50331648 + 65536);            // 16 KiB

    prep_kernel<<<M_DIM + N_DIM, 256, 0, stream>>>(x, q8, scl, azp, w, w8, adj);
    dim3 grid(N_DIM / 256, M_DIM / 256);
    gemm_kernel<<<grid, 512, 0, stream>>>(q8, w8, scl, azp, adj, wscale, bias, out);
}

// Round 4
// 402.394 us; speedup vs baseline: 3.4893x; 3.4893x over previous
//
#include <hip/hip_runtime.h>
#include <cstdint>
#include <cstddef>

// out[m,n] = scale[m]*wscale[n]*(sum_k q[m,k]*w8[n,k] - azp[m]*azp_adj[n]) + bias[n]
// M=8192, K=4096, N=4096. Exact int8 path.

#define M_DIM 8192
#define K_DIM 4096
#define N_DIM 4096
#define NT 64   // K tiles of BK=64

typedef int v4i __attribute__((ext_vector_type(4)));

// ---------------------------------------------------------------------------
// Kernel 1 (fused): blocks [0, M) do per-token quant; blocks [M, M+N) do
// weight prep. Bit-identical math to the verified standalone kernels.
// ---------------------------------------------------------------------------
__global__ __launch_bounds__(256) void prep_kernel(
    const float* __restrict__ x, signed char* __restrict__ q,
    float* __restrict__ scale_out, int* __restrict__ azp_out,
    const int* __restrict__ w, signed char* __restrict__ w8,
    int* __restrict__ azp_adj)
{
    const int t = threadIdx.x;
    if (blockIdx.x < M_DIM) {
        // ---- per-token asymmetric quantization, one block per row ----
        const int m = blockIdx.x;
        const float4* row4 = (const float4*)(x + (size_t)m * K_DIM);

        float4 v[4];
        float mx = -3.4e38f, mn = 3.4e38f;
#pragma unroll
        for (int i = 0; i < 4; ++i) {
            v[i] = row4[i * 256 + t];                  // coalesced
            mx = fmaxf(mx, fmaxf(fmaxf(v[i].x, v[i].y), fmaxf(v[i].z, v[i].w)));
            mn = fminf(mn, fminf(fminf(v[i].x, v[i].y), fminf(v[i].z, v[i].w)));
        }
#pragma unroll
        for (int off = 32; off; off >>= 1) {
            mx = fmaxf(mx, __shfl_down(mx, off));
            mn = fminf(mn, __shfl_down(mn, off));
        }
        __shared__ float smx[4], smn[4];
        if ((t & 63) == 0) { smx[t >> 6] = mx; smn[t >> 6] = mn; }
        __syncthreads();
        mx = fmaxf(fmaxf(smx[0], smx[1]), fmaxf(smx[2], smx[3]));
        mn = fminf(fminf(smn[0], smn[1]), fminf(smn[2], smn[3]));

        const float scale = (mx - mn) / 255.0f;
        const int azp = (int)rintf(-128.0f - mn / scale);
        if (t == 0) { scale_out[m] = scale; azp_out[m] = azp; }

        int* qrow = (int*)(q + (size_t)m * K_DIM);
        const float* vf = (const float*)v;
#pragma unroll
        for (int i = 0; i < 4; ++i) {
            int b[4];
#pragma unroll
            for (int j = 0; j < 4; ++j) {
                int qv = (int)rintf(vf[4 * i + j] / scale) + azp;
                qv = qv < -128 ? -128 : (qv > 127 ? 127 : qv);
                b[j] = qv;
            }
            qrow[i * 256 + t] =
                (b[0] & 255) | ((b[1] & 255) << 8) | ((b[2] & 255) << 16) | ((b[3] & 255) << 24);
        }
    } else {
        // ---- weight prep: int32 [N,K] -> int8 [N,K] + column sums ----
        const int n = blockIdx.x - M_DIM;
        const int4* row = (const int4*)(w + (size_t)n * K_DIM);
        int* w8row = (int*)(w8 + (size_t)n * K_DIM);
        int sum = 0;
#pragma unroll
        for (int i = 0; i < 4; ++i) {
            int4 a = row[i * 256 + t];                 // coalesced
            sum += a.x + a.y + a.z + a.w;
            w8row[i * 256 + t] =
                (a.x & 255) | ((a.y & 255) << 8) | ((a.z & 255) << 16) | ((a.w & 255) << 24);
        }
#pragma unroll
        for (int off = 32; off; off >>= 1) sum += __shfl_down(sum, off);
        __shared__ int ssum[4];
        if ((t & 63) == 0) ssum[t >> 6] = sum;
        __syncthreads();
        if (t == 0) azp_adj[n] = ssum[0] + ssum[1] + ssum[2] + ssum[3];
    }
}

// ---------------------------------------------------------------------------
// Kernel 2: int8 GEMM, 256x256 tile, BK=64, 8 waves (2M x 4N), per-wave
// 128x64 via mfma_i32_16x16x64_i8.
//
// Round-4: round-1's proven memory schedule (ring-4 LDS, prefetch-3, counted
// vmcnt(8) -- never drains) + WITHIN-WAVE READ-AHEAD with counted lgkmcnt:
// every ds_read is issued one phase before its consuming MFMA cluster, so
// the LDS pipe (~800-1100 cy/tile) runs UNDER the MFMA pipe (~1306 cy/tile)
// instead of serializing with it (round-1 measured 3056 cy/tile, serial).
//   ph1: stage(kt+3); issue ah; vmcnt(8); barrier; lgkmcnt(4) [lands af/bf,
//        issued last phase]; sched_barrier; 16 MFMA(af x bf); barrier
//   ph2: issue next tile's af'/bf' (buffer sealed by ph1's vmcnt+barrier);
//        lgkmcnt(8) [lands ah]; sched_barrier; 16 MFMA(ah x bf); barrier
// lgkm bookkeeping (steady state): enter ph1 with 8 outstanding (af/bf);
// +4 (ah) -> lgkm(4) completes af/bf. Enter ph2 with 4; +8 -> lgkm(8)
// completes ah. sched_barrier(0) after each wait per rule 18 (hipcc hoists
// register-only MFMA past inline-asm waitcnt).
//
// Race safety:
//   - vmcnt(8) BEFORE ph1's barrier: all waves' stages for buf kt+1 retired
//     before any wave passes the barrier and (in ph2) reads buf kt+1.
//   - stage(kt+3) writes buf (kt-1)&3: its reads (af/bf drained at kt's ph1
//     lgkm(4); ah drained at (kt-1)'s ph2 lgkm) all retire before the
//     end-of-tile-(kt-1) barrier; stage issued after it.
//   - __launch_bounds__(512, 2): round-3's (512,4) capped regs at 128 ->
//     acc spilled to scratch (VGPR=64, WRITE_SIZE 3.6 GB). Never again.
//   - XOR swizzle byte-identical to the proven kernel (0 conflicts measured).
//   - XCD-aware bijective block swizzle (512 blocks, 512 % 8 == 0).
// ---------------------------------------------------------------------------
__device__ __forceinline__ void async_copy16(const signed char* g, signed char* l) {
    __builtin_amdgcn_global_load_lds(
        (const __attribute__((address_space(1))) void*)g,
        (__attribute__((address_space(3))) void*)l, 16, 0, 0);
}

template<int RO>
__device__ __forceinline__ void mfma16(const v4i (&x)[4], const v4i (&y)[4], v4i (&acc)[8][4]) {
#pragma unroll
    for (int i = 0; i < 4; ++i)
#pragma unroll
        for (int j = 0; j < 4; ++j)
            acc[RO + i][j] = __builtin_amdgcn_mfma_i32_16x16x64_i8(x[i], y[j], acc[RO + i][j], 0, 0, 0);
}

template<int CUR, bool STG, int VMN, bool RA>
__device__ __forceinline__ void tile_body(
    int kt, signed char (*sA)[16384], signed char (*sB)[16384],
    const signed char* ag0, const signed char* ag1,
    const signed char* bg0, const signed char* bg1,
    int t, int aIdx, int bIdx,
    v4i (&af)[4], v4i (&bf)[4],      // this tile's frags (in flight on entry)
    v4i (&afn)[4], v4i (&bfn)[4],    // next tile's frags (issued in ph2)
    v4i (&acc)[8][4])
{
    const v4i* a4 = (const v4i*)&sA[CUR][0];

    // ---- phase 1 ----
    if constexpr (STG) {
        const int ko = (kt + 3) << 6;
        signed char* dA = &sA[(CUR + 3) & 3][0];
        signed char* dB = &sB[(CUR + 3) & 3][0];
        async_copy16(ag0 + ko, dA + t * 16);
        async_copy16(ag1 + ko, dA + 8192 + t * 16);
        async_copy16(bg0 + ko, dB + t * 16);
        async_copy16(bg1 + ko, dB + 8192 + t * 16);
    }
    v4i ah[4];
#pragma unroll
    for (int i = 0; i < 4; ++i) ah[i] = a4[aIdx + 256 + i * 64];   // rows wm+64+i*16+r16
    if constexpr (VMN == 8)      asm volatile("s_waitcnt vmcnt(8)" ::: "memory");
    else if constexpr (VMN == 4) asm volatile("s_waitcnt vmcnt(4)" ::: "memory");
    else if constexpr (VMN == 0) asm volatile("s_waitcnt vmcnt(0)" ::: "memory");
    asm volatile("s_barrier" ::: "memory");
    asm volatile("s_waitcnt lgkmcnt(4)" ::: "memory");   // af/bf landed; ah in flight
    __builtin_amdgcn_sched_barrier(0);
    __builtin_amdgcn_s_setprio(1);
    mfma16<0>(af, bf, acc);
    __builtin_amdgcn_s_setprio(0);
    asm volatile("s_barrier" ::: "memory");

    // ---- phase 2 ----
    if constexpr (RA) {
        const v4i* a4n = (const v4i*)&sA[(CUR + 1) & 3][0];
        const v4i* b4n = (const v4i*)&sB[(CUR + 1) & 3][0];
#pragma unroll
        for (int i = 0; i < 4; ++i) {
            afn[i] = a4n[aIdx + i * 64];
            bfn[i] = b4n[bIdx + i * 64];
        }
        asm volatile("s_waitcnt lgkmcnt(8)" ::: "memory");  // ah landed; af'/bf' fly
    } else {
        asm volatile("s_waitcnt lgkmcnt(0)" ::: "memory");
    }
    __builtin_amdgcn_sched_barrier(0);
    __builtin_amdgcn_s_setprio(1);
    mfma16<4>(ah, bf, acc);
    __builtin_amdgcn_s_setprio(0);
    asm volatile("s_barrier" ::: "memory");
}

__global__ __launch_bounds__(512, 2) void gemm_kernel(
    const signed char* __restrict__ A,   // [M,K] quantized activations
    const signed char* __restrict__ B,   // [N,K] int8 weights
    const float* __restrict__ scale, const int* __restrict__ azp,
    const int* __restrict__ azp_adj, const float* __restrict__ wscale,
    const float* __restrict__ bias, float* __restrict__ out)
{
    __shared__ signed char sA[4][16384];   // 4-deep ring x 256 rows x 64B
    __shared__ signed char sB[4][16384];   // total 128 KiB, 1 block/CU

    const int t = threadIdx.x;
    const int lane = t & 63;
    const int wave = t >> 6;
    const int quad = lane >> 4;
    const int r16 = lane & 15;

    // XCD-aware swizzle over the 512 blocks (bijective since 512 % 8 == 0)
    int bid = blockIdx.y * gridDim.x + blockIdx.x;
    bid = (bid & 7) * 64 + (bid >> 3);
    const int bn = (bid & 15) << 8;        // 16 n-blocks
    const int bm = (bid >> 4) << 8;        // 32 m-blocks

    const int wm = (wave >> 2) << 7;       // 0 or 128
    const int wn = (wave & 3) << 6;        // 0,64,128,192

    v4i acc[8][4];
#pragma unroll
    for (int i = 0; i < 8; ++i)
#pragma unroll
        for (int j = 0; j < 4; ++j) acc[i][j] = (v4i){0, 0, 0, 0};

    // staging: thread t fills LDS granule t of a 128-row chunk (row = t>>2,
    // colL = t&3); global col = colL ^ ((row>>1)&3) = (t&3) ^ ((t>>3)&3).
    const int srow = t >> 2;                               // 0..127
    const int scol = ((t & 3) ^ ((t >> 3) & 3)) << 4;      // pre-swizzled global col
    const signed char* ag0 = A + (size_t)(bm + srow) * K_DIM + scol;
    const signed char* ag1 = A + (size_t)(bm + 128 + srow) * K_DIM + scol;
    const signed char* bg0 = B + (size_t)(bn + srow) * K_DIM + scol;
    const signed char* bg1 = B + (size_t)(bn + 128 + srow) * K_DIM + scol;

#define STAGE_A(kt) do { const int _b = (kt) & 3; const int _ko = (kt) << 6; \
    async_copy16(ag0 + _ko, &sA[_b][t * 16]); \
    async_copy16(ag1 + _ko, &sA[_b][8192 + t * 16]); } while (0)
#define STAGE_B(kt) do { const int _b = (kt) & 3; const int _ko = (kt) << 6; \
    async_copy16(bg0 + _ko, &sB[_b][t * 16]); \
    async_copy16(bg1 + _ko, &sB[_b][8192 + t * 16]); } while (0)

    // per-lane LDS read indices (v4i granule units); swizzle collapses to a
    // per-lane constant since wm/wn/i*16 are 0 mod 8.
    const int swz = quad ^ ((r16 >> 1) & 3);
    const int aIdx = (wm + r16) * 4 + swz;   // granule index within one buffer
    const int bIdx = (wn + r16) * 4 + swz;

    // prologue: fill tiles 0,1,2; seal tile 0; issue its af/bf
    STAGE_A(0); STAGE_B(0);
    STAGE_A(1); STAGE_B(1);
    STAGE_A(2); STAGE_B(2);
    asm volatile("s_waitcnt vmcnt(8)" ::: "memory");
    asm volatile("s_barrier" ::: "memory");

    v4i afA[4], bfA[4], afB[4], bfB[4];
    {
        const v4i* a4 = (const v4i*)&sA[0][0];
        const v4i* b4 = (const v4i*)&sB[0][0];
#pragma unroll
        for (int i = 0; i < 4; ++i) {
            afA[i] = a4[aIdx + i * 64];
            bfA[i] = b4[bIdx + i * 64];
        }
    }

    // main loop: 4-tile unroll keeps ring indices compile-time (rule 20);
    // frag sets alternate A/B per tile
    for (int kt = 0; kt < NT - 4; kt += 4) {
        tile_body<0, true, 8, true>(kt,     sA, sB, ag0, ag1, bg0, bg1, t, aIdx, bIdx, afA, bfA, afB, bfB, acc);
        tile_body<1, true, 8, true>(kt + 1, sA, sB, ag0, ag1, bg0, bg1, t, aIdx, bIdx, afB, bfB, afA, bfA, acc);
        tile_body<2, true, 8, true>(kt + 2, sA, sB, ag0, ag1, bg0, bg1, t, aIdx, bIdx, afA, bfA, afB, bfB, acc);
        tile_body<3, true, 8, true>(kt + 3, sA, sB, ag0, ag1, bg0, bg1, t, aIdx, bIdx, afB, bfB, afA, bfA, acc);
    }
    // peeled tail: tiles 60..63 (stages end at 63 = issued in tile 60)
    tile_body<0, true,  8, true >(NT - 4, sA, sB, ag0, ag1, bg0, bg1, t, aIdx, bIdx, afA, bfA, afB, bfB, acc);
    tile_body<1, false, 4, true >(NT - 3, sA, sB, ag0, ag1, bg0, bg1, t, aIdx, bIdx, afB, bfB, afA, bfA, acc);
    tile_body<2, false, 0, true >(NT - 2, sA, sB, ag0, ag1, bg0, bg1, t, aIdx, bIdx, afA, bfA, afB, bfB, acc);
    tile_body<3, false, -1, false>(NT - 1, sA, sB, ag0, ag1, bg0, bg1, t, aIdx, bIdx, afB, bfB, afA, bfA, acc);

#undef STAGE_A
#undef STAGE_B

    // epilogue: out = scale[m]*wscale[n]*(acc - azp[m]*adj[n]) + bias[n]
#pragma unroll
    for (int i = 0; i < 8; ++i) {
        const int mbase = bm + wm + i * 16 + quad * 4;
        float sm[4]; int am[4];
#pragma unroll
        for (int r = 0; r < 4; ++r) { sm[r] = scale[mbase + r]; am[r] = azp[mbase + r]; }
#pragma unroll
        for (int j = 0; j < 4; ++j) {
            const int n = bn + wn + j * 16 + r16;
            const float wsn = wscale[n];
            const int adjn = azp_adj[n];
            const float bn_ = bias[n];
#pragma unroll
            for (int r = 0; r < 4; ++r) {
                const int c = acc[i][j][r] - am[r] * adjn;
                out[(size_t)(mbase + r) * N_DIM + n] = sm[r] * wsn * (float)c + bn_;
            }
        }
    }
}

// ---------------------------------------------------------------------------
extern "C" void kernel_launch(void* const* d_in, const int* in_sizes, int n_in,
                              void* d_out, int out_size, void* d_ws, size_t ws_size,
                              hipStream_t stream) {
    const float* x      = (const float*)d_in[0];
    const int*   w      = (const int*)d_in[1];
    const float* wscale = (const float*)d_in[2];
    const float* bias   = (const float*)d_in[3];
    float* out = (float*)d_out;

    char* ws = (char*)d_ws;
    signed char* q8  = (signed char*)ws;                         // 32 MiB
    signed char* w8  = (signed char*)(ws + 33554432);            // 16 MiB
    float* scl       = (float*)(ws + 50331648);                  // 32 KiB
    int*   azp       = (int*)(ws + 50331648 + 32768);            // 32 KiB
    int*   adj       = (int*)(ws + 50331648 + 65536);            // 16 KiB

    prep_kernel<<<M_DIM + N_DIM, 256, 0, stream>>>(x, q8, scl, azp, w, w8, adj);
    dim3 grid(N_DIM / 256, M_DIM / 256);
    gemm_kernel<<<grid, 512, 0, stream>>>(q8, w8, scl, azp, adj, wscale, bias, out);
}